// Round 12
// baseline (425.839 us; speedup 1.0000x reference)
//
#include <hip/hip_runtime.h>
#include <math.h>

#define NCLS      16
#define B_ROWS    65536
#define MARGINc   1.0f
#define CHUNK     64
#define CPC       128      // chunks per class (covers cnt <= 8192)
#define NCHUNK    (NCLS * CPC)   // 2048

// ws float offsets — every region write-before-read each call
#define F_CE     0
#define F_CNT    32        // 16 int
#define F_OFFS   48        // 16 int
#define F_INV    64        // 16 f32
#define F_CTR    128       // int counter (ce_hist last-block)
#define F_CTR2   129       // int counter (dist last-block)
#define F_CEPART 256       // 256 f32
#define F_HIST   1024      // 16*256 int  (hist[c*256 + b])
#define F_BASES  8192      // 16*256 int  (class-LOCAL prefix; scatter adds offs)
#define F_CENT   16384     // 16384 f32
#define F_ORDER  32768     // 65536 int
#define F_DISTP  98304     // 2048 f32
#define F_PART   131072    // 16*128*1024 f32 (8.4 MB)

#define CADD(V) { acc.x += V.x; acc.y += V.y; acc.z += V.z; acc.w += V.w; }
#define DSQ(V, C) { float dx = V.x - C.x, dy = V.y - C.y, dz = V.z - C.z, dw = V.w - C.w; \
                    accT += dx * dx + dy * dy + dz * dz + dw * dw; }

// CE + per-block class histogram; LAST block (device counter) runs the prefix
// + CE total inline (release/acquire via __threadfence + device atomicAdd).
__global__ __launch_bounds__(256) void k_ce_hist(const float* __restrict__ logits,
                                                 const int* __restrict__ labels,
                                                 float* __restrict__ ws) {
    __shared__ int hist[NCLS];
    __shared__ float cew[4];
    __shared__ int ctot[NCLS];
    __shared__ int islast;
    int tid = threadIdx.x, lane = tid & 63, w = tid >> 6;
    int b = blockIdx.x;
    int* wsi = (int*)ws;
    if (tid < NCLS) hist[tid] = 0;
    __syncthreads();
    int row = b * 256 + tid;
    const float4* lg = (const float4*)(logits + (size_t)row * 16);
    float4 a = lg[0], b4 = lg[1], c = lg[2], d = lg[3];
    float m = fmaxf(fmaxf(fmaxf(a.x, a.y), fmaxf(a.z, a.w)),
                    fmaxf(fmaxf(b4.x, b4.y), fmaxf(b4.z, b4.w)));
    m = fmaxf(m, fmaxf(fmaxf(c.x, c.y), fmaxf(c.z, c.w)));
    m = fmaxf(m, fmaxf(fmaxf(d.x, d.y), fmaxf(d.z, d.w)));
    float s = expf(a.x - m) + expf(a.y - m) + expf(a.z - m) + expf(a.w - m)
            + expf(b4.x - m) + expf(b4.y - m) + expf(b4.z - m) + expf(b4.w - m)
            + expf(c.x - m) + expf(c.y - m) + expf(c.z - m) + expf(c.w - m)
            + expf(d.x - m) + expf(d.y - m) + expf(d.z - m) + expf(d.w - m);
    int lab = labels[row];
    atomicAdd(&hist[lab], 1);
    float xl = logits[(size_t)row * 16 + lab];
    float ce = (m + logf(s)) - xl;
    for (int o = 32; o >= 1; o >>= 1) ce += __shfl_down(ce, o, 64);
    if (lane == 0) cew[w] = ce;
    __syncthreads();
    if (tid == 0) ws[F_CEPART + b] = cew[0] + cew[1] + cew[2] + cew[3];
    if (tid < NCLS) wsi[F_HIST + tid * 256 + b] = hist[tid];

    // ---- last-block prefix ----
    __threadfence();                                  // release hist/cepart
    if (tid == 0) islast = (atomicAdd(wsi + F_CTR, 1) == 255);
    __syncthreads();
    if (!islast) return;
    __threadfence();                                  // acquire others' stores
    const int* histg = wsi + F_HIST;
    int* bases = wsi + F_BASES;
    for (int ci = 0; ci < 4; ++ci) {                  // wave w -> class w*4+ci
        int cc = w * 4 + ci;
        int base = lane * 4;
        int v0 = histg[cc * 256 + base + 0];
        int v1 = histg[cc * 256 + base + 1];
        int v2 = histg[cc * 256 + base + 2];
        int v3 = histg[cc * 256 + base + 3];
        int tot = v0 + v1 + v2 + v3;
        int x = tot;
        for (int o = 1; o < 64; o <<= 1) {
            int y = __shfl_up(x, o, 64);
            if (lane >= o) x += y;
        }
        int excl = x - tot;
        bases[cc * 256 + base + 0] = excl;            // class-local prefix
        bases[cc * 256 + base + 1] = excl + v0;
        bases[cc * 256 + base + 2] = excl + v0 + v1;
        bases[cc * 256 + base + 3] = excl + v0 + v1 + v2;
        if (lane == 63) ctot[cc] = x;
    }
    __syncthreads();
    if (tid == 0) {
        int off = 0;
        for (int cc = 0; cc < NCLS; ++cc) {
            int cnt = ctot[cc];
            wsi[F_CNT + cc] = cnt;
            wsi[F_OFFS + cc] = off;
            ws[F_INV + cc] = 1.0f / (float)(cnt > 0 ? cnt : 1);
            off += cnt;
        }
    }
    float sv = ws[F_CEPART + tid];                    // 256 partials, 1/thread
    for (int o = 32; o >= 1; o >>= 1) sv += __shfl_down(sv, o, 64);
    if (lane == 0) cew[w] = sv;
    __syncthreads();
    if (tid == 0) ws[F_CE] = cew[0] + cew[1] + cew[2] + cew[3];
}

// counting-sort scatter (LDS cursors = class offset + class-local base)
__global__ __launch_bounds__(256) void k_scatter(const int* __restrict__ labels,
                                                 float* __restrict__ ws) {
    __shared__ int cur[NCLS];
    int tid = threadIdx.x, b = blockIdx.x;
    int* wsi = (int*)ws;
    if (tid < NCLS) cur[tid] = wsi[F_OFFS + tid] + wsi[F_BASES + tid * 256 + b];
    __syncthreads();
    int row = b * 256 + tid;
    int lab = labels[row];
    int pos = atomicAdd(&cur[lab], 1);
    wsi[F_ORDER + pos] = row;
}

// class sums: ONE block per 64-row chunk (grid 2048), register accumulate
__global__ __launch_bounds__(256) void k_csums(const float* __restrict__ feat,
                                               float* __restrict__ ws) {
    int tid = threadIdx.x;
    int vc = blockIdx.x;                       // grid NCHUNK
    int c = vc >> 7, k = vc & (CPC - 1);
    const int* cnts  = (const int*)ws + F_CNT;
    const int* offs  = (const int*)ws + F_OFFS;
    const int* order = (const int*)ws + F_ORDER;
    const float4* f4 = (const float4*)feat;
    float4* part4 = (float4*)(ws + F_PART);

    int cnt = cnts[c];
    int s0 = k * CHUNK;
    float4 acc = make_float4(0.f, 0.f, 0.f, 0.f);
    if (s0 < cnt) {
        int e = s0 + CHUNK; if (e > cnt) e = cnt;
        const int* ord = order + offs[c] + s0;
        int n = e - s0;
        int i = 0;
        for (; i + 8 <= n; i += 8) {
            int i0 = ord[i], i1 = ord[i + 1], i2 = ord[i + 2], i3 = ord[i + 3];
            int i4 = ord[i + 4], i5 = ord[i + 5], i6 = ord[i + 6], i7 = ord[i + 7];
            float4 v0 = f4[(size_t)i0 * 256 + tid];
            float4 v1 = f4[(size_t)i1 * 256 + tid];
            float4 v2 = f4[(size_t)i2 * 256 + tid];
            float4 v3 = f4[(size_t)i3 * 256 + tid];
            float4 v4 = f4[(size_t)i4 * 256 + tid];
            float4 v5 = f4[(size_t)i5 * 256 + tid];
            float4 v6 = f4[(size_t)i6 * 256 + tid];
            float4 v7 = f4[(size_t)i7 * 256 + tid];
            CADD(v0) CADD(v1) CADD(v2) CADD(v3)
            CADD(v4) CADD(v5) CADD(v6) CADD(v7)
        }
        for (; i < n; ++i) {
            float4 v = f4[(size_t)ord[i] * 256 + tid];
            CADD(v)
        }
    }
    part4[(size_t)vc * 256 + tid] = acc;       // zeros for empty chunks too
}

// partial reduce -> centroids (x inv count); partials zero-padded
__global__ __launch_bounds__(128) void k_cent(float* __restrict__ ws) {
    int j = blockIdx.x * 128 + threadIdx.x;    // grid 128 -> 16384
    int c = j >> 10, d = j & 1023;
    int cnt = ((const int*)ws)[F_CNT + c];
    int kmax = (cnt + CHUNK - 1) >> 6;
    const float* part = ws + F_PART + (size_t)c * CPC * 1024 + d;
    float s = 0.f;
    int k = 0;
    for (; k + 4 <= kmax; k += 4)
        s += part[(size_t)k * 1024] + part[(size_t)(k + 1) * 1024]
           + part[(size_t)(k + 2) * 1024] + part[(size_t)(k + 3) * 1024];
    for (; k < kmax; ++k) s += part[(size_t)k * 1024];
    ws[F_CENT + j] = s * ws[F_INV + c];
}

// distances (reverse chunk order, centroid in registers); LAST block runs the
// final combine inline (same release/acquire pattern).
__global__ __launch_bounds__(256) void k_dist(const float* __restrict__ feat,
                                              float* __restrict__ ws,
                                              float* __restrict__ out) {
    __shared__ float red4[4];
    __shared__ float redf[256];
    __shared__ float winter[4];
    __shared__ int wcnt[4];
    __shared__ int islast;
    int tid = threadIdx.x, lane = tid & 63, w = tid >> 6;
    int vc = (NCHUNK - 1) - blockIdx.x;        // reverse mapping
    int c = vc >> 7, k = vc & (CPC - 1);
    int* wsi = (int*)ws;
    const int* cnts  = wsi + F_CNT;
    const int* offs  = wsi + F_OFFS;
    const int* order = wsi + F_ORDER;
    const float4* f4 = (const float4*)feat;
    const float4* c4 = (const float4*)(ws + F_CENT);
    float* distp = ws + F_DISTP;

    int cnt = cnts[c];
    int s0 = k * CHUNK;
    if (s0 >= cnt) {
        if (tid == 0) distp[vc] = 0.f;
    } else {
        int n = cnt - s0; if (n > CHUNK) n = CHUNK;
        const int* ord = order + offs[c] + s0;
        float4 c0 = c4[c * 256 + 0 * 64 + lane];
        float4 c1 = c4[c * 256 + 1 * 64 + lane];
        float4 c2 = c4[c * 256 + 2 * 64 + lane];
        float4 c3 = c4[c * 256 + 3 * 64 + lane];
        float wsum = 0.f;
        int rbeg = w * 16;
        int rend = rbeg + 16; if (rend > n) rend = n;
        int i = rbeg;
        for (; i + 2 <= rend; i += 2) {
            int ra = ord[i], rb = ord[i + 1];
            float4 va0 = f4[(size_t)ra * 256 + 0 * 64 + lane];
            float4 va1 = f4[(size_t)ra * 256 + 1 * 64 + lane];
            float4 va2 = f4[(size_t)ra * 256 + 2 * 64 + lane];
            float4 va3 = f4[(size_t)ra * 256 + 3 * 64 + lane];
            float4 vb0 = f4[(size_t)rb * 256 + 0 * 64 + lane];
            float4 vb1 = f4[(size_t)rb * 256 + 1 * 64 + lane];
            float4 vb2 = f4[(size_t)rb * 256 + 2 * 64 + lane];
            float4 vb3 = f4[(size_t)rb * 256 + 3 * 64 + lane];
            float accT;
            accT = 0.f; DSQ(va0, c0) DSQ(va1, c1) DSQ(va2, c2) DSQ(va3, c3)
            float accA = accT;
            accT = 0.f; DSQ(vb0, c0) DSQ(vb1, c1) DSQ(vb2, c2) DSQ(vb3, c3)
            float accB = accT;
            for (int o = 32; o >= 1; o >>= 1) {
                accA += __shfl_down(accA, o, 64);
                accB += __shfl_down(accB, o, 64);
            }
            if (lane == 0) wsum += sqrtf(accA) + sqrtf(accB);
        }
        if (i < rend) {
            int ra = ord[i];
            float4 va0 = f4[(size_t)ra * 256 + 0 * 64 + lane];
            float4 va1 = f4[(size_t)ra * 256 + 1 * 64 + lane];
            float4 va2 = f4[(size_t)ra * 256 + 2 * 64 + lane];
            float4 va3 = f4[(size_t)ra * 256 + 3 * 64 + lane];
            float accT = 0.f;
            DSQ(va0, c0) DSQ(va1, c1) DSQ(va2, c2) DSQ(va3, c3)
            for (int o = 32; o >= 1; o >>= 1) accT += __shfl_down(accT, o, 64);
            if (lane == 0) wsum += sqrtf(accT);
        }
        if (lane == 0) red4[w] = wsum;
        __syncthreads();
        if (tid == 0) distp[vc] = red4[0] + red4[1] + red4[2] + red4[3];
    }

    // ---- last-block final combine ----
    __threadfence();                                  // release distp
    if (tid == 0) islast = (atomicAdd(wsi + F_CTR2, 1) == NCHUNK - 1);
    __syncthreads();
    if (!islast) return;
    __threadfence();                                  // acquire others' distp

    // distp reduce: thread (g,c0) sums chunks k = g, g+16, ... (CPC=128)
    int c0 = tid & 15, g = tid >> 4;
    float s = 0.f;
    for (int kk = g; kk < CPC; kk += 16) s += distp[(c0 << 7) + kk];
    redf[tid] = s;
    __syncthreads();

    float interAcc = 0.f; int pairAcc = 0;
    for (int p = w; p < 120; p += 4) {
        int i = 0, rem = p;
        while (rem >= 15 - i) { rem -= 15 - i; ++i; }
        int j = i + 1 + rem;
        int ci = cnts[i], cj = cnts[j];
        float acc = 0.f;
#pragma unroll
        for (int kk = 0; kk < 4; ++kk) {
            float4 a = c4[i * 256 + kk * 64 + lane];
            float4 b = c4[j * 256 + kk * 64 + lane];
            float dx = a.x - b.x, dy = a.y - b.y, dz = a.z - b.z, dw = a.w - b.w;
            acc += dx * dx + dy * dy + dz * dz + dw * dw;
        }
        for (int o = 32; o >= 1; o >>= 1) acc += __shfl_down(acc, o, 64);
        if (lane == 0 && ci > 0 && cj > 0) {
            float t = MARGINc - sqrtf(acc);
            if (t > 0.f) interAcc += t;
            pairAcc += 1;
        }
    }
    if (lane == 0) { winter[w] = interAcc; wcnt[w] = pairAcc; }
    __syncthreads();
    if (tid == 0) {
        float interSum = winter[0] + winter[1] + winter[2] + winter[3];
        int np = wcnt[0] + wcnt[1] + wcnt[2] + wcnt[3];
        float inter = np > 0 ? interSum / (float)np : 0.f;
        float intra = 0.f; int nv = 0;
        for (int cc = 0; cc < NCLS; ++cc) {
            float dsum = 0.f;
            for (int gg = 0; gg < 16; ++gg) dsum += redf[gg * 16 + cc];
            if (cnts[cc] > 0) { intra += dsum * ws[F_INV + cc]; nv++; }
        }
        intra = nv > 0 ? intra / (float)nv : 0.f;
        float ce = ws[F_CE] / (float)B_ROWS;
        out[0] = ce + inter + intra;
    }
}

extern "C" void kernel_launch(void* const* d_in, const int* in_sizes, int n_in,
                              void* d_out, int out_size, void* d_ws, size_t ws_size,
                              hipStream_t stream) {
    const float* logits = (const float*)d_in[0];
    const int* labels   = (const int*)d_in[1];
    const float* feat   = (const float*)d_in[2];
    float* ws  = (float*)d_ws;
    float* out = (float*)d_out;

    // zero the two last-block counters (graph-legal memset node)
    hipMemsetAsync((char*)d_ws + F_CTR * 4, 0, 8, stream);

    hipLaunchKernelGGL(k_ce_hist, dim3(256),    dim3(256), 0, stream, logits, labels, ws);
    hipLaunchKernelGGL(k_scatter, dim3(256),    dim3(256), 0, stream, labels, ws);
    hipLaunchKernelGGL(k_csums,   dim3(NCHUNK), dim3(256), 0, stream, feat, ws);
    hipLaunchKernelGGL(k_cent,    dim3(128),    dim3(128), 0, stream, ws);
    hipLaunchKernelGGL(k_dist,    dim3(NCHUNK), dim3(256), 0, stream, feat, ws, out);
}

// Round 13
// 136.976 us; speedup vs baseline: 3.1088x; 3.1088x over previous
//
#include <hip/hip_runtime.h>
#include <math.h>

#define NCLS      16
#define B_ROWS    65536
#define MARGINc   1.0f
#define CHUNK     64
#define CPC       128      // chunks per class (covers cnt <= 8192)
#define NCHUNK    (NCLS * CPC)   // 2048

// ws float offsets — every region write-before-read each call
#define F_CE     0
#define F_CNT    32        // 16 int
#define F_OFFS   48        // 16 int
#define F_INV    64        // 16 f32
#define F_CEPART 256       // 256 f32
#define F_HIST   1024      // 16*256 int  (hist[c*256 + b])
#define F_BASES  8192      // 16*256 int
#define F_CENT   16384     // 16384 f32
#define F_ORDER  32768     // 65536 int
#define F_DISTP  98304     // 2048 f32
#define F_PART   131072    // 16*128*1024 f32 (8.4 MB)

#define CADD(V) { acc.x += V.x; acc.y += V.y; acc.z += V.z; acc.w += V.w; }
#define DSQ(V, C) { float dx = V.x - C.x, dy = V.y - C.y, dz = V.z - C.z, dw = V.w - C.w; \
                    accT += dx * dx + dy * dy + dz * dz + dw * dw; }

// CE + per-block class histogram (R7-proven). 256 blocks x 256 rows.
__global__ __launch_bounds__(256) void k_ce_hist(const float* __restrict__ logits,
                                                 const int* __restrict__ labels,
                                                 float* __restrict__ ws) {
    __shared__ int hist[NCLS];
    __shared__ float cew[4];
    int tid = threadIdx.x, lane = tid & 63, w = tid >> 6;
    int b = blockIdx.x;
    if (tid < NCLS) hist[tid] = 0;
    __syncthreads();
    int row = b * 256 + tid;
    const float4* lg = (const float4*)(logits + (size_t)row * 16);
    float4 a = lg[0], b4 = lg[1], c = lg[2], d = lg[3];
    float m = fmaxf(fmaxf(fmaxf(a.x, a.y), fmaxf(a.z, a.w)),
                    fmaxf(fmaxf(b4.x, b4.y), fmaxf(b4.z, b4.w)));
    m = fmaxf(m, fmaxf(fmaxf(c.x, c.y), fmaxf(c.z, c.w)));
    m = fmaxf(m, fmaxf(fmaxf(d.x, d.y), fmaxf(d.z, d.w)));
    float s = expf(a.x - m) + expf(a.y - m) + expf(a.z - m) + expf(a.w - m)
            + expf(b4.x - m) + expf(b4.y - m) + expf(b4.z - m) + expf(b4.w - m)
            + expf(c.x - m) + expf(c.y - m) + expf(c.z - m) + expf(c.w - m)
            + expf(d.x - m) + expf(d.y - m) + expf(d.z - m) + expf(d.w - m);
    int lab = labels[row];
    atomicAdd(&hist[lab], 1);
    float xl = logits[(size_t)row * 16 + lab];
    float ce = (m + logf(s)) - xl;
    for (int o = 32; o >= 1; o >>= 1) ce += __shfl_down(ce, o, 64);
    if (lane == 0) cew[w] = ce;
    __syncthreads();
    if (tid == 0) ws[F_CEPART + b] = cew[0] + cew[1] + cew[2] + cew[3];
    if (tid < NCLS) ((int*)ws)[F_HIST + tid * 256 + b] = hist[tid];
}

// One 1024-thread block (wave = class): scan per-block counts -> bases, etc.
__global__ __launch_bounds__(1024) void k_prefix(float* __restrict__ ws) {
    __shared__ int ctot[NCLS];
    __shared__ float cew[4];
    int tid = threadIdx.x, lane = tid & 63, w = tid >> 6;
    const int* hist = (const int*)ws + F_HIST;
    int* bases = (int*)ws + F_BASES;
    int base = lane * 4;
    int v0 = hist[w * 256 + base + 0];
    int v1 = hist[w * 256 + base + 1];
    int v2 = hist[w * 256 + base + 2];
    int v3 = hist[w * 256 + base + 3];
    int tot = v0 + v1 + v2 + v3;
    int x = tot;
    for (int o = 1; o < 64; o <<= 1) {
        int y = __shfl_up(x, o, 64);
        if (lane >= o) x += y;
    }
    int excl = x - tot;
    if (lane == 63) ctot[w] = x;
    __syncthreads();
    int off = 0;
    for (int cc = 0; cc < NCLS; ++cc) if (cc < w) off += ctot[cc];
    bases[w * 256 + base + 0] = off + excl;
    bases[w * 256 + base + 1] = off + excl + v0;
    bases[w * 256 + base + 2] = off + excl + v0 + v1;
    bases[w * 256 + base + 3] = off + excl + v0 + v1 + v2;
    if (lane == 0) {
        int cnt = ctot[w];
        ((int*)ws)[F_CNT + w] = cnt;
        ((int*)ws)[F_OFFS + w] = off;
        ws[F_INV + w] = 1.0f / (float)(cnt > 0 ? cnt : 1);
    }
    float s = (tid < 256) ? ws[F_CEPART + tid] : 0.f;
    if (tid < 256) {
        for (int o = 32; o >= 1; o >>= 1) s += __shfl_down(s, o, 64);
        if (lane == 0) cew[w] = s;
    }
    __syncthreads();
    if (tid == 0) ws[F_CE] = cew[0] + cew[1] + cew[2] + cew[3];
}

// counting-sort scatter (LDS cursors from bases)
__global__ __launch_bounds__(256) void k_scatter(const int* __restrict__ labels,
                                                 float* __restrict__ ws) {
    __shared__ int cur[NCLS];
    int tid = threadIdx.x, b = blockIdx.x;
    if (tid < NCLS) cur[tid] = ((int*)ws)[F_BASES + tid * 256 + b];
    __syncthreads();
    int row = b * 256 + tid;
    int lab = labels[row];
    int pos = atomicAdd(&cur[lab], 1);
    ((int*)ws)[F_ORDER + pos] = row;
}

// class sums: ONE block per 64-row chunk (grid 2048), register accumulate,
// flush = plain float4 store
__global__ __launch_bounds__(256) void k_csums(const float* __restrict__ feat,
                                               float* __restrict__ ws) {
    int tid = threadIdx.x;
    int vc = blockIdx.x;                       // grid NCHUNK
    int c = vc >> 7, k = vc & (CPC - 1);
    const int* cnts  = (const int*)ws + F_CNT;
    const int* offs  = (const int*)ws + F_OFFS;
    const int* order = (const int*)ws + F_ORDER;
    const float4* f4 = (const float4*)feat;
    float4* part4 = (float4*)(ws + F_PART);

    int cnt = cnts[c];
    int s0 = k * CHUNK;
    float4 acc = make_float4(0.f, 0.f, 0.f, 0.f);
    if (s0 < cnt) {
        int e = s0 + CHUNK; if (e > cnt) e = cnt;
        const int* ord = order + offs[c] + s0;
        int n = e - s0;
        int i = 0;
        for (; i + 8 <= n; i += 8) {
            int i0 = ord[i], i1 = ord[i + 1], i2 = ord[i + 2], i3 = ord[i + 3];
            int i4 = ord[i + 4], i5 = ord[i + 5], i6 = ord[i + 6], i7 = ord[i + 7];
            float4 v0 = f4[(size_t)i0 * 256 + tid];
            float4 v1 = f4[(size_t)i1 * 256 + tid];
            float4 v2 = f4[(size_t)i2 * 256 + tid];
            float4 v3 = f4[(size_t)i3 * 256 + tid];
            float4 v4 = f4[(size_t)i4 * 256 + tid];
            float4 v5 = f4[(size_t)i5 * 256 + tid];
            float4 v6 = f4[(size_t)i6 * 256 + tid];
            float4 v7 = f4[(size_t)i7 * 256 + tid];
            CADD(v0) CADD(v1) CADD(v2) CADD(v3)
            CADD(v4) CADD(v5) CADD(v6) CADD(v7)
        }
        for (; i < n; ++i) {
            float4 v = f4[(size_t)ord[i] * 256 + tid];
            CADD(v)
        }
    }
    part4[(size_t)vc * 256 + tid] = acc;       // store zeros for empty chunks too
}

// partial reduce -> centroids (x inv count); partials are zero-padded
__global__ __launch_bounds__(256) void k_cent(float* __restrict__ ws) {
    int j = blockIdx.x * 256 + threadIdx.x;    // grid 64 -> 16384
    int c = j >> 10, d = j & 1023;
    int cnt = ((const int*)ws)[F_CNT + c];
    int kmax = (cnt + CHUNK - 1) >> 6;
    const float* part = ws + F_PART + (size_t)c * CPC * 1024 + d;
    float s = 0.f;
    int k = 0;
    for (; k + 4 <= kmax; k += 4)
        s += part[(size_t)k * 1024] + part[(size_t)(k + 1) * 1024]
           + part[(size_t)(k + 2) * 1024] + part[(size_t)(k + 3) * 1024];
    for (; k < kmax; ++k) s += part[(size_t)k * 1024];
    ws[F_CENT + j] = s * ws[F_INV + c];
}

// distances: ONE block per chunk, REVERSE of csums order (L3 stack reuse);
// class is chunk-uniform -> centroid in 4 registers/lane
__global__ __launch_bounds__(256) void k_dist(const float* __restrict__ feat,
                                              float* __restrict__ ws) {
    __shared__ float red[4];
    int tid = threadIdx.x, lane = tid & 63, w = tid >> 6;
    int vc = (NCHUNK - 1) - blockIdx.x;        // reverse mapping
    int c = vc >> 7, k = vc & (CPC - 1);
    const int* cnts  = (const int*)ws + F_CNT;
    const int* offs  = (const int*)ws + F_OFFS;
    const int* order = (const int*)ws + F_ORDER;
    const float4* f4 = (const float4*)feat;
    const float4* c4 = (const float4*)(ws + F_CENT);
    float* distp = ws + F_DISTP;

    int cnt = cnts[c];
    int s0 = k * CHUNK;
    if (s0 >= cnt) { if (tid == 0) distp[vc] = 0.f; return; }
    int n = cnt - s0; if (n > CHUNK) n = CHUNK;
    const int* ord = order + offs[c] + s0;

    float4 c0 = c4[c * 256 + 0 * 64 + lane];
    float4 c1 = c4[c * 256 + 1 * 64 + lane];
    float4 c2 = c4[c * 256 + 2 * 64 + lane];
    float4 c3 = c4[c * 256 + 3 * 64 + lane];

    float wsum = 0.f;
    int rbeg = w * 16;
    int rend = rbeg + 16; if (rend > n) rend = n;
    int i = rbeg;
    for (; i + 2 <= rend; i += 2) {
        int ra = ord[i], rb = ord[i + 1];
        float4 va0 = f4[(size_t)ra * 256 + 0 * 64 + lane];
        float4 va1 = f4[(size_t)ra * 256 + 1 * 64 + lane];
        float4 va2 = f4[(size_t)ra * 256 + 2 * 64 + lane];
        float4 va3 = f4[(size_t)ra * 256 + 3 * 64 + lane];
        float4 vb0 = f4[(size_t)rb * 256 + 0 * 64 + lane];
        float4 vb1 = f4[(size_t)rb * 256 + 1 * 64 + lane];
        float4 vb2 = f4[(size_t)rb * 256 + 2 * 64 + lane];
        float4 vb3 = f4[(size_t)rb * 256 + 3 * 64 + lane];
        float accT;
        accT = 0.f; DSQ(va0, c0) DSQ(va1, c1) DSQ(va2, c2) DSQ(va3, c3)
        float accA = accT;
        accT = 0.f; DSQ(vb0, c0) DSQ(vb1, c1) DSQ(vb2, c2) DSQ(vb3, c3)
        float accB = accT;
        for (int o = 32; o >= 1; o >>= 1) {
            accA += __shfl_down(accA, o, 64);
            accB += __shfl_down(accB, o, 64);
        }
        if (lane == 0) wsum += sqrtf(accA) + sqrtf(accB);
    }
    if (i < rend) {
        int ra = ord[i];
        float4 va0 = f4[(size_t)ra * 256 + 0 * 64 + lane];
        float4 va1 = f4[(size_t)ra * 256 + 1 * 64 + lane];
        float4 va2 = f4[(size_t)ra * 256 + 2 * 64 + lane];
        float4 va3 = f4[(size_t)ra * 256 + 3 * 64 + lane];
        float accT = 0.f;
        DSQ(va0, c0) DSQ(va1, c1) DSQ(va2, c2) DSQ(va3, c3)
        for (int o = 32; o >= 1; o >>= 1) accT += __shfl_down(accT, o, 64);
        if (lane == 0) wsum += sqrtf(accT);
    }
    if (lane == 0) red[w] = wsum;
    __syncthreads();
    if (tid == 0) distp[vc] = red[0] + red[1] + red[2] + red[3];
}

// single block: dist-chunk reduce + inter-class pairs + combine
__global__ __launch_bounds__(256) void k_final(float* __restrict__ ws, float* __restrict__ out) {
    __shared__ float red[256];
    __shared__ float winter[4];
    __shared__ int wcnt[4];
    int tid = threadIdx.x, lane = tid & 63, w = tid >> 6;
    const int* cnts = (const int*)ws + F_CNT;

    // distp reduce: thread (g,c) sums chunks k = g, g+16, ... (CPC=128)
    int c0 = tid & 15, g = tid >> 4;
    const float* dp = ws + F_DISTP;
    float s = 0.f;
    for (int k = g; k < CPC; k += 16) s += dp[(c0 << 7) + k];
    red[tid] = s;
    __syncthreads();

    const float4* c4 = (const float4*)(ws + F_CENT);
    float interAcc = 0.f; int pairAcc = 0;
    for (int p = w; p < 120; p += 4) {
        int i = 0, rem = p;
        while (rem >= 15 - i) { rem -= 15 - i; ++i; }
        int j = i + 1 + rem;
        int ci = cnts[i], cj = cnts[j];
        float acc = 0.f;
#pragma unroll
        for (int k = 0; k < 4; ++k) {
            float4 a = c4[i * 256 + k * 64 + lane];
            float4 b = c4[j * 256 + k * 64 + lane];
            float dx = a.x - b.x, dy = a.y - b.y, dz = a.z - b.z, dw = a.w - b.w;
            acc += dx * dx + dy * dy + dz * dz + dw * dw;
        }
        for (int o = 32; o >= 1; o >>= 1) acc += __shfl_down(acc, o, 64);
        if (lane == 0 && ci > 0 && cj > 0) {
            float t = MARGINc - sqrtf(acc);
            if (t > 0.f) interAcc += t;
            pairAcc += 1;
        }
    }
    if (lane == 0) { winter[w] = interAcc; wcnt[w] = pairAcc; }
    __syncthreads();
    if (tid == 0) {
        float interSum = winter[0] + winter[1] + winter[2] + winter[3];
        int np = wcnt[0] + wcnt[1] + wcnt[2] + wcnt[3];
        float inter = np > 0 ? interSum / (float)np : 0.f;
        float intra = 0.f; int nv = 0;
        for (int cc = 0; cc < NCLS; ++cc) {
            float dsum = 0.f;
            for (int gg = 0; gg < 16; ++gg) dsum += red[gg * 16 + cc];
            if (cnts[cc] > 0) { intra += dsum * ws[F_INV + cc]; nv++; }
        }
        intra = nv > 0 ? intra / (float)nv : 0.f;
        float ce = ws[F_CE] / (float)B_ROWS;
        out[0] = ce + inter + intra;
    }
}

extern "C" void kernel_launch(void* const* d_in, const int* in_sizes, int n_in,
                              void* d_out, int out_size, void* d_ws, size_t ws_size,
                              hipStream_t stream) {
    const float* logits = (const float*)d_in[0];
    const int* labels   = (const int*)d_in[1];
    const float* feat   = (const float*)d_in[2];
    float* ws  = (float*)d_ws;
    float* out = (float*)d_out;

    hipLaunchKernelGGL(k_ce_hist, dim3(256),    dim3(256),  0, stream, logits, labels, ws);
    hipLaunchKernelGGL(k_prefix,  dim3(1),      dim3(1024), 0, stream, ws);
    hipLaunchKernelGGL(k_scatter, dim3(256),    dim3(256),  0, stream, labels, ws);
    hipLaunchKernelGGL(k_csums,   dim3(NCHUNK), dim3(256),  0, stream, feat, ws);
    hipLaunchKernelGGL(k_cent,    dim3(64),     dim3(256),  0, stream, ws);
    hipLaunchKernelGGL(k_dist,    dim3(NCHUNK), dim3(256),  0, stream, feat, ws);
    hipLaunchKernelGGL(k_final,   dim3(1),      dim3(256),  0, stream, ws, out);
}